// Round 4
// baseline (257.056 us; speedup 1.0000x reference)
//
#include <hip/hip_runtime.h>
#include <float.h>

// VectorQuantizer: B=16,T=4096,D=256,K=1024 fp32.
// Round 6: BARRIER-FREE main loop. The f16 codebook (512 KB) is L2-resident,
//   so LDS staging of code tiles was pure overhead (2-phase barrier+drain
//   structure = the measured 72%-stall regime). vq_prep now writes the
//   codebook directly in MFMA A-fragment tiled order; vq_main streams
//   af fragments from L2 with coalesced dwordx4 loads — no ds_write/ds_read,
//   no __syncthreads in the K-loop. Per-chunk cross-half merges replaced by
//   per-wave running top-2 in registers (associative; exact-tie divergence
//   across halves has gap 0 < margin -> always rescued).
//   Numerics: identical MFMA fragments, order, and -0.5*c2 init as verified.
//   Score space: score = x.c - 0.5*c2  (argmin d2 == argmax score).

typedef _Float16 f16;
typedef f16 f16x8 __attribute__((ext_vector_type(8)));
typedef f16 f16x4 __attribute__((ext_vector_type(4)));
typedef float f32x4 __attribute__((ext_vector_type(4)));

#define DDIM    256
#define KCODES  1024
#define NTOK    65536
#define SMARGIN 0.1f   // score-space margin; == 0.2 in d2 units (d2 gap = 2*score gap)

// ---------------- prep: codebook fp32 -> A-fragment-tiled f16, c2, zero count ----
// Tiled layout: cht[((ct*8 + kt)*64 + L)*8 + j] = f16(cb[ct*16 + (L&15)][kt*32 + (L>>4)*8 + j])
//   (exactly the 16x16x32 MFMA A-operand per-lane layout; ct = code tile, kt = k tile)
__global__ __launch_bounds__(256) void vq_prep(const float* __restrict__ cb,
                                               f16* __restrict__ cht,
                                               float* __restrict__ c2,
                                               unsigned* __restrict__ count) {
    const int k    = blockIdx.x * 4 + (threadIdx.x >> 6);
    const int lane = threadIdx.x & 63;
    const float4 v = *(const float4*)(cb + (size_t)k * DDIM + 4 * lane);
    f16x4 h; h[0] = (f16)v.x; h[1] = (f16)v.y; h[2] = (f16)v.z; h[3] = (f16)v.w;
    const int ct = k >> 4, m = k & 15;
    const int e  = 4 * lane;            // this thread's 4 consecutive k-elements
    const int kt = e >> 5;
    const int s  = (e & 31) >> 3;       // sub-lane group within k-tile
    const int j0 = e & 7;               // 0 or 4
    const int L  = s * 16 + m;          // fragment lane
    *(f16x4*)(cht + ((size_t)(ct * 8 + kt) * 64 + L) * 8 + j0) = h;
    float ssum = v.x * v.x + v.y * v.y + v.z * v.z + v.w * v.w;
    #pragma unroll
    for (int off = 32; off > 0; off >>= 1) ssum += __shfl_down(ssum, off, 64);
    if (lane == 0) c2[k] = ssum;
    if (blockIdx.x == 0 && threadIdx.x == 0) *count = 0u;
}

// ---------------- main: L2-streamed MFMA distances + register argmax + gather ------
__global__ __launch_bounds__(256, 2) void vq_main(const float* __restrict__ xg,
                                                  const f16* __restrict__ cht,
                                                  const float* __restrict__ c2,
                                                  const float* __restrict__ cb,
                                                  float* __restrict__ out,
                                                  unsigned* __restrict__ count,
                                                  unsigned* __restrict__ list) {
    __shared__ float c2s[KCODES];
    __shared__ float wmv[2][128];              // per code-half best score
    __shared__ int   wmi[2][128];
    __shared__ float wms[2][128];              // per code-half second score
    __shared__ int   idx_s[128];

    const int t    = threadIdx.x;
    const int wave = t >> 6, lane = t & 63;
    const int wm   = wave >> 1;                // code-half (M)
    const int tn   = wave & 1;                 // token-half (N)
    const int q    = lane >> 4;                // operand quad
    const int m16  = lane & 15;
    const int tok0 = blockIdx.x * 128;

    // ---- load token B-fragments, fp32 -> f16 in registers (once; verified) ----
    f16x8 bfrag[4][8];
    #pragma unroll
    for (int ti = 0; ti < 4; ++ti) {
        const size_t row = (size_t)(tok0 + tn * 64 + ti * 16 + m16) * DDIM;
        #pragma unroll
        for (int ks = 0; ks < 8; ++ks) {
            const float* p = xg + row + ks * 32 + q * 8;
            const float4 u0 = *(const float4*)(p);
            const float4 u1 = *(const float4*)(p + 4);
            f16x8 b;
            b[0] = (f16)u0.x; b[1] = (f16)u0.y; b[2] = (f16)u0.z; b[3] = (f16)u0.w;
            b[4] = (f16)u1.x; b[5] = (f16)u1.y; b[6] = (f16)u1.z; b[7] = (f16)u1.w;
            bfrag[ti][ks] = b;
        }
    }

    *(float4*)&c2s[t * 4] = *(const float4*)(c2 + t * 4);
    __syncthreads();                           // c2s visible (only pre-loop barrier)

    // running top-2 per ti over this wave's code-half, in registers
    float rb1[4], rb2[4]; int ri1[4];
    #pragma unroll
    for (int ti = 0; ti < 4; ++ti) { rb1[ti] = -FLT_MAX; rb2[ti] = -FLT_MAX; ri1[ti] = 0; }

    const f16* aw = cht + wm * 16384 + lane * 8;   // wave's A-fragment base

    #pragma unroll 1
    for (int nc = 0; nc < 8; ++nc) {           // 8 chunks of 128 codes
        f32x4 acc[4][4];                       // [ci][ti], init = -0.5*c2 (score space)
        #pragma unroll
        for (int ci = 0; ci < 4; ++ci) {
            f32x4 cv = *(const f32x4*)&c2s[nc * 128 + wm * 64 + ci * 16 + q * 4];
            cv = cv * -0.5f;
            #pragma unroll
            for (int ti = 0; ti < 4; ++ti) acc[ci][ti] = cv;
        }

        const f16* an = aw + nc * 32768;
        #pragma unroll
        for (int ks = 0; ks < 8; ++ks) {       // K=256 in 8 slices of 32
            f16x8 af[4];
            #pragma unroll
            for (int ci = 0; ci < 4; ++ci)
                af[ci] = *(const f16x8*)(an + ci * 4096 + ks * 512);
            #pragma unroll
            for (int ci = 0; ci < 4; ++ci)
                #pragma unroll
                for (int ti = 0; ti < 4; ++ti)
                    acc[ci][ti] = __builtin_amdgcn_mfma_f32_16x16x32_f16(
                        af[ci], bfrag[ti][ks], acc[ci][ti], 0, 0, 0);
        }

        // ---- chunk epilogue: per-token top-2 over this half's 64 codes ----
        const int kbase = nc * 128 + wm * 64;
        #pragma unroll
        for (int ti = 0; ti < 4; ++ti) {
            float b1 = -FLT_MAX, b2 = -FLT_MAX; int i1 = 0;
            #pragma unroll
            for (int ci = 0; ci < 4; ++ci) {   // ascending code order within lane
                #pragma unroll
                for (int r = 0; r < 4; ++r) {
                    const float v = acc[ci][ti][r];
                    const int   c = kbase + ci * 16 + q * 4 + r;
                    const bool gt = v > b1;    // strict: tie keeps lower index
                    b2 = fmaxf(b2, gt ? b1 : v);
                    i1 = gt ? c : i1;
                    b1 = gt ? v : b1;
                }
            }
            #pragma unroll
            for (int sft = 0; sft < 2; ++sft) {  // merge quads (l^16, l^32)
                const int off = 16 << sft;
                const float ob1 = __shfl_xor(b1, off, 64);
                const float ob2 = __shfl_xor(b2, off, 64);
                const int   oi1 = __shfl_xor(i1, off, 64);
                const bool better = (ob1 > b1) || (ob1 == b1 && oi1 < i1);
                b2 = fmaxf(fmaxf(b2, ob2), fminf(b1, ob1));
                b1 = better ? ob1 : b1;
                i1 = better ? oi1 : i1;
            }
            // fold into running (ascending nc -> earlier chunk wins ties)
            rb2[ti] = fmaxf(fmaxf(rb2[ti], b2), fminf(rb1[ti], b1));
            if (b1 > rb1[ti]) { rb1[ti] = b1; ri1[ti] = i1; }
        }
    }

    // ---- publish per-half results, merge halves, flag, gather ----
    #pragma unroll
    for (int ti = 0; ti < 4; ++ti) {
        if (lane < 16) {
            const int tl = tn * 64 + ti * 16 + m16;
            wmv[wm][tl] = rb1[ti]; wmi[wm][tl] = ri1[ti]; wms[wm][tl] = rb2[ti];
        }
    }
    __syncthreads();
    if (t < 128) {
        const float a1 = wmv[0][t], a2 = wms[0][t];
        const int   ai = wmi[0][t];
        const float b1_ = wmv[1][t], b2_ = wms[1][t];
        const int   bi_ = wmi[1][t];
        const bool bb = (b1_ > a1) || (b1_ == a1 && bi_ < ai);
        const float c1 = bb ? b1_ : a1;
        const int   ci_ = bb ? bi_ : ai;
        const float cs = fmaxf(fmaxf(a2, b2_), fminf(a1, b1_));
        idx_s[t] = ci_;
        if (c1 - cs < SMARGIN) {               // d2 gap = 2*(c1-cs) < 0.2
            const unsigned p = atomicAdd(count, 1u);
            list[p] = tok0 + t;
        }
    }
    __syncthreads();

    // gather epilogue: out[tok] = cb[argmin], coalesced float4
    #pragma unroll
    for (int i = 0; i < 32; ++i) {
        const int f   = i * 256 + t;           // 8192 float4 = 128 tok x 64
        const int tok = f >> 6, d4 = f & 63;
        const int code = idx_s[tok];
        const float4 v = *(const float4*)(cb + (size_t)code * DDIM + 4 * d4);
        *(float4*)(out + (size_t)(tok0 + tok) * DDIM + 4 * d4) = v;
    }
}

// ---------------- rescue: exact fp32 argmin for margin-flagged tokens ----------------
// (unchanged from round 5: 8 tokens/iter, no spill, grid-stride 1024)
__global__ __launch_bounds__(256) void vq_rescue(const float* __restrict__ xg,
                                                 const float* __restrict__ cb,
                                                 const float* __restrict__ c2,
                                                 const unsigned* __restrict__ count,
                                                 const unsigned* __restrict__ list,
                                                 float* __restrict__ out) {
    __shared__ float xls[8][DDIM];             // 8 KB
    __shared__ float rv[4][8];
    __shared__ int   ri[4][8];
    __shared__ int   bidx[8];

    const int t = threadIdx.x;
    const int wave = t >> 6, lane = t & 63;
    const unsigned n = *count;

    for (unsigned base = blockIdx.x * 8; base < n; base += gridDim.x * 8) {
        const int nb = (int)min(8u, n - base);
        __syncthreads();                        // protect xls/rv/bidx reuse
        #pragma unroll
        for (int i = 0; i < 2; ++i) {
            const int f = t + 256 * i;          // 512 float4 slots
            const int row = f >> 6, d4 = f & 63;
            if (row < nb)
                *(float4*)&xls[row][4 * d4] =
                    *(const float4*)(xg + (size_t)list[base + row] * DDIM + 4 * d4);
        }
        __syncthreads();

        float acc[4][8];
        #pragma unroll
        for (int j = 0; j < 4; ++j)
            #pragma unroll
            for (int tk = 0; tk < 8; ++tk) acc[j][tk] = 0.0f;

        for (int d4 = 0; d4 < 64; ++d4) {
            float4 cv[4];
            #pragma unroll
            for (int j = 0; j < 4; ++j)
                cv[j] = *(const float4*)(cb + (size_t)(4 * t + j) * DDIM + 4 * d4);
            #pragma unroll
            for (int tk = 0; tk < 8; ++tk) {
                const float4 xv = *(const float4*)&xls[tk][4 * d4];
                #pragma unroll
                for (int j = 0; j < 4; ++j) {
                    float a = acc[j][tk];       // sequential .x->.w: verified order
                    a = fmaf(cv[j].x, xv.x, a);
                    a = fmaf(cv[j].y, xv.y, a);
                    a = fmaf(cv[j].z, xv.z, a);
                    a = fmaf(cv[j].w, xv.w, a);
                    acc[j][tk] = a;
                }
            }
        }

        // per-token argmin: thread's 4 codes -> wave butterfly -> cross-wave merge
        #pragma unroll
        for (int tk = 0; tk < 8; ++tk) {
            if (tk < nb) {
                float b1 = FLT_MAX; int i1 = 0;
                #pragma unroll
                for (int j = 0; j < 4; ++j) {   // codes 4t..4t+3 ascending
                    const float d = fmaf(-2.0f, acc[j][tk], c2[4 * t + j]);
                    if (d < b1) { b1 = d; i1 = 4 * t + j; }
                }
                #pragma unroll
                for (int off = 32; off > 0; off >>= 1) {
                    const float ov = __shfl_xor(b1, off, 64);
                    const int   oi = __shfl_xor(i1, off, 64);
                    if (ov < b1 || (ov == b1 && oi < i1)) { b1 = ov; i1 = oi; }
                }
                if (lane == 0) { rv[wave][tk] = b1; ri[wave][tk] = i1; }
            }
        }
        __syncthreads();
        if (t < 8 && t < nb) {                  // ascending wave order: same tiebreak
            float bv = rv[0][t]; int bi = ri[0][t];
            #pragma unroll
            for (int w = 1; w < 4; ++w)
                if (rv[w][t] < bv || (rv[w][t] == bv && ri[w][t] < bi)) {
                    bv = rv[w][t]; bi = ri[w][t];
                }
            bidx[t] = bi;
        }
        __syncthreads();

        #pragma unroll
        for (int i = 0; i < 2; ++i) {
            const int f = t + 256 * i;
            const int row = f >> 6, d4 = f & 63;
            if (row < nb) {
                const int code = bidx[row];
                const float4 v = *(const float4*)(cb + (size_t)code * DDIM + 4 * d4);
                *(float4*)(out + (size_t)list[base + row] * DDIM + 4 * d4) = v;
            }
        }
    }
}

extern "C" void kernel_launch(void* const* d_in, const int* in_sizes, int n_in,
                              void* d_out, int out_size, void* d_ws, size_t ws_size,
                              hipStream_t stream) {
    const float* x  = (const float*)d_in[0];   // [B,T,D] fp32
    const float* cb = (const float*)d_in[1];   // [K,D]   fp32
    float* out = (float*)d_out;

    char* ws = (char*)d_ws;
    f16*      cht   = (f16*)ws;                              // 524288 B (tiled)
    float*    c2    = (float*)(ws + 524288);                 // 4096 B
    unsigned* count = (unsigned*)(ws + 528448);              // 4 B (padded)
    unsigned* list  = (unsigned*)(ws + 528512);              // 262144 B

    hipLaunchKernelGGL(vq_prep,   dim3(KCODES / 4), dim3(256), 0, stream, cb, cht, c2, count);
    hipLaunchKernelGGL(vq_main,   dim3(NTOK / 128), dim3(256), 0, stream,
                       x, cht, c2, cb, out, count, list);
    hipLaunchKernelGGL(vq_rescue, dim3(1024),       dim3(256), 0, stream,
                       x, cb, c2, count, list, out);
}

// Round 5
// 232.075 us; speedup vs baseline: 1.1076x; 1.1076x over previous
//
#include <hip/hip_runtime.h>
#include <float.h>

// VectorQuantizer: B=16,T=4096,D=256,K=1024 fp32.
// Round 7: WAVE-PRIVATE LDS staging, ZERO barriers in the K-loop.
//   Round-3 retro-diagnosis: __syncthreads drains vmcnt(0) -> per-stage L2
//   latency serialized (81us). Round-4: no LDS buffer -> raw L2 chain (108us).
//   Fix: each wave stages its own 64x64 f16 tile in a private 8KB LDS region;
//   intra-wave LDS ops are in-order -> ds_write/ds_read need no barrier, WAR
//   on a single buffer is program-order-safe. One-stage-ahead sreg prefetch
//   is never drained. 2x codebook L2 reads (~512MB agg) fully overlapped.
//   Swizzle, fragments, accumulation order byte-identical to verified r3;
//   epilogue/merge = verified r4 register top-2; prep/rescue = verified r5.
//   Score space: score = x.c - 0.5*c2  (argmin d2 == argmax score).

typedef _Float16 f16;
typedef f16 f16x8 __attribute__((ext_vector_type(8)));
typedef f16 f16x4 __attribute__((ext_vector_type(4)));
typedef float f32x4 __attribute__((ext_vector_type(4)));

#define DDIM    256
#define KCODES  1024
#define NTOK    65536
#define SMARGIN 0.1f   // score-space margin; == 0.2 in d2 units (d2 gap = 2*score gap)

// ---------------- prep: codebook fp32->f16 (row-major), c2, zero counter ----------------
__global__ __launch_bounds__(256) void vq_prep(const float* __restrict__ cb,
                                               f16* __restrict__ ch,
                                               float* __restrict__ c2,
                                               unsigned* __restrict__ count) {
    const int k    = blockIdx.x * 4 + (threadIdx.x >> 6);
    const int lane = threadIdx.x & 63;
    const float4 v = *(const float4*)(cb + (size_t)k * DDIM + 4 * lane);
    f16x4 h; h[0] = (f16)v.x; h[1] = (f16)v.y; h[2] = (f16)v.z; h[3] = (f16)v.w;
    *(f16x4*)(ch + (size_t)k * DDIM + 4 * lane) = h;
    float s = v.x * v.x + v.y * v.y + v.z * v.z + v.w * v.w;
    #pragma unroll
    for (int off = 32; off > 0; off >>= 1) s += __shfl_down(s, off, 64);
    if (lane == 0) c2[k] = s;
    if (blockIdx.x == 0 && threadIdx.x == 0) *count = 0u;
}

// ---------------- main: wave-private staged MFMA + register argmax + gather ----------
// Per wave, per stage (nc,st): private tile = code rows [nc*128+wm*64 .. +63],
// k-cols [st*64 .. +63]. LDS slot (r, C ^ ((r&7)<<4)) holds element (r, C).
//   write: lane stages rows (lane>>3)+8i, granule (lane&7); swizzle const/lane.
//   read : row ci*16+m16, col ((kk<<6)|(q<<4)) ^ ((m16&7)<<4). 2-way banks only.
__global__ __launch_bounds__(256, 2) void vq_main(const float* __restrict__ xg,
                                                  const f16* __restrict__ ch,
                                                  const float* __restrict__ c2,
                                                  const float* __restrict__ cb,
                                                  float* __restrict__ out,
                                                  unsigned* __restrict__ count,
                                                  unsigned* __restrict__ list) {
    __shared__ f16   As[4 * 4096];             // 4 waves x 8 KB private tiles
    __shared__ float c2s[KCODES];
    __shared__ float wmv[2][128];              // per code-half best score
    __shared__ int   wmi[2][128];
    __shared__ float wms[2][128];              // per code-half second score
    __shared__ int   idx_s[128];

    const int t    = threadIdx.x;
    const int wave = t >> 6, lane = t & 63;
    const int wm   = wave >> 1;                // code-half (M)
    const int tn   = wave & 1;                 // token-half (N)
    const int q    = lane >> 4;                // operand quad
    const int m16  = lane & 15;
    const int tok0 = blockIdx.x * 128;
    const int swz  = (m16 & 7) << 4;           // read-side swizzle
    const int wswz = ((lane & 7) ^ (lane >> 3)) << 4;  // write-side swizzle (const/lane)
    const int r0   = lane >> 3;                // staged rows r0 + 8i
    const int g0   = (lane & 7) * 8;           // staged col granule (f16 units)

    // ---- load token B-fragments, fp32 -> f16 in registers (once; verified) ----
    f16x8 bfrag[4][8];
    #pragma unroll
    for (int ti = 0; ti < 4; ++ti) {
        const size_t row = (size_t)(tok0 + tn * 64 + ti * 16 + m16) * DDIM;
        #pragma unroll
        for (int ks = 0; ks < 8; ++ks) {
            const float* p = xg + row + ks * 32 + q * 8;
            const float4 u0 = *(const float4*)(p);
            const float4 u1 = *(const float4*)(p + 4);
            f16x8 b;
            b[0] = (f16)u0.x; b[1] = (f16)u0.y; b[2] = (f16)u0.z; b[3] = (f16)u0.w;
            b[4] = (f16)u1.x; b[5] = (f16)u1.y; b[6] = (f16)u1.z; b[7] = (f16)u1.w;
            bfrag[ti][ks] = b;
        }
    }

    *(float4*)&c2s[t * 4] = *(const float4*)(c2 + t * 4);

    // prologue: prefetch stage (0,0) into sreg
    f16x8 sreg[8];
    #pragma unroll
    for (int i = 0; i < 8; ++i)
        sreg[i] = *(const f16x8*)(ch + (size_t)(wm * 64 + r0 + 8 * i) * DDIM + g0);

    __syncthreads();                           // c2s visible (only pre-loop barrier)

    // running top-2 per ti over this wave's code-half, in registers
    float rb1[4], rb2[4]; int ri1[4];
    #pragma unroll
    for (int ti = 0; ti < 4; ++ti) { rb1[ti] = -FLT_MAX; rb2[ti] = -FLT_MAX; ri1[ti] = 0; }

    char* wb = (char*)As + wave * 8192;        // this wave's private tile

    for (int nc = 0; nc < 8; ++nc) {           // 8 chunks of 128 codes
        f32x4 acc[4][4];                       // [ci][ti], init = -0.5*c2 (score space)
        #pragma unroll
        for (int ci = 0; ci < 4; ++ci) {
            f32x4 cv = *(const f32x4*)&c2s[nc * 128 + wm * 64 + ci * 16 + q * 4];
            cv = cv * -0.5f;
            #pragma unroll
            for (int ti = 0; ti < 4; ++ti) acc[ci][ti] = cv;
        }

        #pragma unroll
        for (int st = 0; st < 4; ++st) {       // BK=64 stages, single private buffer
            // ---- write staged regs -> private tile (in-order after prior reads) ----
            #pragma unroll
            for (int i = 0; i < 8; ++i)
                *(f16x8*)(wb + (r0 + 8 * i) * 128 + wswz) = sreg[i];
            // ---- prefetch next stage (no barrier will ever drain it) ----
            if (!(nc == 7 && st == 3)) {
                const int nn = nc + (st == 3 ? 1 : 0);
                const int ns = (st + 1) & 3;
                #pragma unroll
                for (int i = 0; i < 8; ++i)
                    sreg[i] = *(const f16x8*)(ch + (size_t)(nn * 128 + wm * 64 + r0 + 8 * i) * DDIM
                                              + ns * 64 + g0);
            }
            // ---- read fragments + 32 MFMA (in-order LDS: sees this wave's writes) ----
            __builtin_amdgcn_s_setprio(1);
            #pragma unroll
            for (int kk = 0; kk < 2; ++kk) {
                const int col = ((kk << 6) | (q << 4)) ^ swz;
                f16x8 af[4];
                #pragma unroll
                for (int ci = 0; ci < 4; ++ci)
                    af[ci] = *(const f16x8*)(wb + (ci * 16 + m16) * 128 + col);
                #pragma unroll
                for (int ci = 0; ci < 4; ++ci)
                    #pragma unroll
                    for (int ti = 0; ti < 4; ++ti)
                        acc[ci][ti] = __builtin_amdgcn_mfma_f32_16x16x32_f16(
                            af[ci], bfrag[ti][st * 2 + kk], acc[ci][ti], 0, 0, 0);
            }
            __builtin_amdgcn_s_setprio(0);
        }

        // ---- chunk epilogue: per-token top-2 over this half's 64 codes (verified) ----
        const int kbase = nc * 128 + wm * 64;
        #pragma unroll
        for (int ti = 0; ti < 4; ++ti) {
            float b1 = -FLT_MAX, b2 = -FLT_MAX; int i1 = 0;
            #pragma unroll
            for (int ci = 0; ci < 4; ++ci) {   // ascending code order within lane
                #pragma unroll
                for (int r = 0; r < 4; ++r) {
                    const float v = acc[ci][ti][r];
                    const int   c = kbase + ci * 16 + q * 4 + r;
                    const bool gt = v > b1;    // strict: tie keeps lower index
                    b2 = fmaxf(b2, gt ? b1 : v);
                    i1 = gt ? c : i1;
                    b1 = gt ? v : b1;
                }
            }
            #pragma unroll
            for (int sft = 0; sft < 2; ++sft) {  // merge quads (l^16, l^32)
                const int off = 16 << sft;
                const float ob1 = __shfl_xor(b1, off, 64);
                const float ob2 = __shfl_xor(b2, off, 64);
                const int   oi1 = __shfl_xor(i1, off, 64);
                const bool better = (ob1 > b1) || (ob1 == b1 && oi1 < i1);
                b2 = fmaxf(fmaxf(b2, ob2), fminf(b1, ob1));
                b1 = better ? ob1 : b1;
                i1 = better ? oi1 : i1;
            }
            // fold into running (ascending nc -> earlier chunk wins ties)
            rb2[ti] = fmaxf(fmaxf(rb2[ti], b2), fminf(rb1[ti], b1));
            if (b1 > rb1[ti]) { rb1[ti] = b1; ri1[ti] = i1; }
        }
    }

    // ---- publish per-half results, merge halves, flag, gather (verified r4) ----
    #pragma unroll
    for (int ti = 0; ti < 4; ++ti) {
        if (lane < 16) {
            const int tl = tn * 64 + ti * 16 + m16;
            wmv[wm][tl] = rb1[ti]; wmi[wm][tl] = ri1[ti]; wms[wm][tl] = rb2[ti];
        }
    }
    __syncthreads();
    if (t < 128) {
        const float a1 = wmv[0][t], a2 = wms[0][t];
        const int   ai = wmi[0][t];
        const float b1_ = wmv[1][t], b2_ = wms[1][t];
        const int   bi_ = wmi[1][t];
        const bool bb = (b1_ > a1) || (b1_ == a1 && bi_ < ai);
        const float c1 = bb ? b1_ : a1;
        const int   ci_ = bb ? bi_ : ai;
        const float cs = fmaxf(fmaxf(a2, b2_), fminf(a1, b1_));
        idx_s[t] = ci_;
        if (c1 - cs < SMARGIN) {               // d2 gap = 2*(c1-cs) < 0.2
            const unsigned p = atomicAdd(count, 1u);
            list[p] = tok0 + t;
        }
    }
    __syncthreads();

    // gather epilogue: out[tok] = cb[argmin], coalesced float4
    #pragma unroll
    for (int i = 0; i < 32; ++i) {
        const int f   = i * 256 + t;           // 8192 float4 = 128 tok x 64
        const int tok = f >> 6, d4 = f & 63;
        const int code = idx_s[tok];
        const float4 v = *(const float4*)(cb + (size_t)code * DDIM + 4 * d4);
        *(float4*)(out + (size_t)(tok0 + tok) * DDIM + 4 * d4) = v;
    }
}

// ---------------- rescue: exact fp32 argmin for margin-flagged tokens ----------------
// (verified round 5: 8 tokens/iter, no spill, grid-stride 1024)
__global__ __launch_bounds__(256) void vq_rescue(const float* __restrict__ xg,
                                                 const float* __restrict__ cb,
                                                 const float* __restrict__ c2,
                                                 const unsigned* __restrict__ count,
                                                 const unsigned* __restrict__ list,
                                                 float* __restrict__ out) {
    __shared__ float xls[8][DDIM];             // 8 KB
    __shared__ float rv[4][8];
    __shared__ int   ri[4][8];
    __shared__ int   bidx[8];

    const int t = threadIdx.x;
    const int wave = t >> 6, lane = t & 63;
    const unsigned n = *count;

    for (unsigned base = blockIdx.x * 8; base < n; base += gridDim.x * 8) {
        const int nb = (int)min(8u, n - base);
        __syncthreads();                        // protect xls/rv/bidx reuse
        #pragma unroll
        for (int i = 0; i < 2; ++i) {
            const int f = t + 256 * i;          // 512 float4 slots
            const int row = f >> 6, d4 = f & 63;
            if (row < nb)
                *(float4*)&xls[row][4 * d4] =
                    *(const float4*)(xg + (size_t)list[base + row] * DDIM + 4 * d4);
        }
        __syncthreads();

        float acc[4][8];
        #pragma unroll
        for (int j = 0; j < 4; ++j)
            #pragma unroll
            for (int tk = 0; tk < 8; ++tk) acc[j][tk] = 0.0f;

        for (int d4 = 0; d4 < 64; ++d4) {
            float4 cv[4];
            #pragma unroll
            for (int j = 0; j < 4; ++j)
                cv[j] = *(const float4*)(cb + (size_t)(4 * t + j) * DDIM + 4 * d4);
            #pragma unroll
            for (int tk = 0; tk < 8; ++tk) {
                const float4 xv = *(const float4*)&xls[tk][4 * d4];
                #pragma unroll
                for (int j = 0; j < 4; ++j) {
                    float a = acc[j][tk];       // sequential .x->.w: verified order
                    a = fmaf(cv[j].x, xv.x, a);
                    a = fmaf(cv[j].y, xv.y, a);
                    a = fmaf(cv[j].z, xv.z, a);
                    a = fmaf(cv[j].w, xv.w, a);
                    acc[j][tk] = a;
                }
            }
        }

        // per-token argmin: thread's 4 codes -> wave butterfly -> cross-wave merge
        #pragma unroll
        for (int tk = 0; tk < 8; ++tk) {
            if (tk < nb) {
                float b1 = FLT_MAX; int i1 = 0;
                #pragma unroll
                for (int j = 0; j < 4; ++j) {   // codes 4t..4t+3 ascending
                    const float d = fmaf(-2.0f, acc[j][tk], c2[4 * t + j]);
                    if (d < b1) { b1 = d; i1 = 4 * t + j; }
                }
                #pragma unroll
                for (int off = 32; off > 0; off >>= 1) {
                    const float ov = __shfl_xor(b1, off, 64);
                    const int   oi = __shfl_xor(i1, off, 64);
                    if (ov < b1 || (ov == b1 && oi < i1)) { b1 = ov; i1 = oi; }
                }
                if (lane == 0) { rv[wave][tk] = b1; ri[wave][tk] = i1; }
            }
        }
        __syncthreads();
        if (t < 8 && t < nb) {                  // ascending wave order: same tiebreak
            float bv = rv[0][t]; int bi = ri[0][t];
            #pragma unroll
            for (int w = 1; w < 4; ++w)
                if (rv[w][t] < bv || (rv[w][t] == bv && ri[w][t] < bi)) {
                    bv = rv[w][t]; bi = ri[w][t];
                }
            bidx[t] = bi;
        }
        __syncthreads();

        #pragma unroll
        for (int i = 0; i < 2; ++i) {
            const int f = t + 256 * i;
            const int row = f >> 6, d4 = f & 63;
            if (row < nb) {
                const int code = bidx[row];
                const float4 v = *(const float4*)(cb + (size_t)code * DDIM + 4 * d4);
                *(float4*)(out + (size_t)list[base + row] * DDIM + 4 * d4) = v;
            }
        }
    }
}

extern "C" void kernel_launch(void* const* d_in, const int* in_sizes, int n_in,
                              void* d_out, int out_size, void* d_ws, size_t ws_size,
                              hipStream_t stream) {
    const float* x  = (const float*)d_in[0];   // [B,T,D] fp32
    const float* cb = (const float*)d_in[1];   // [K,D]   fp32
    float* out = (float*)d_out;

    char* ws = (char*)d_ws;
    f16*      ch    = (f16*)ws;                              // 524288 B
    float*    c2    = (float*)(ws + 524288);                 // 4096 B
    unsigned* count = (unsigned*)(ws + 528448);              // 4 B (padded)
    unsigned* list  = (unsigned*)(ws + 528512);              // 262144 B

    hipLaunchKernelGGL(vq_prep,   dim3(KCODES / 4), dim3(256), 0, stream, cb, ch, c2, count);
    hipLaunchKernelGGL(vq_main,   dim3(NTOK / 128), dim3(256), 0, stream,
                       x, ch, c2, cb, out, count, list);
    hipLaunchKernelGGL(vq_rescue, dim3(1024),       dim3(256), 0, stream,
                       x, cb, c2, count, list, out);
}

// Round 6
// 228.505 us; speedup vs baseline: 1.1249x; 1.0156x over previous
//
#include <hip/hip_runtime.h>
#include <float.h>

// VectorQuantizer: B=16,T=4096,D=256,K=1024 fp32.
// Round 8: direct L2->register A-fragments (round-4 tiled cht, verified) with
//   an EXPLICIT double-buffered af pipeline (afA/afB, static names, ks-loop
//   fully unrolled; loads for slice s+2 issued after slice s's MFMA cluster).
//   Round-4 retro: 0-deep at the 128-VGPR cap -> raw L2 latency per slice.
//   Round-5/7 retro: wave-private LDS staging doubled staged bytes and bound
//   on L1-return + LDS pipes (MfmaUtil pinned ~15%). This removes the LDS
//   round-trip entirely: no ds_write/ds_read, no lgkm chains, LDS ~8KB.
//   Epilogue/merge/gather = verified r4; prep = verified r4 (tiled);
//   rescue = verified r5 (8 tok/iter, grid-stride 1024).
//   Score space: score = x.c - 0.5*c2  (argmin d2 == argmax score).

typedef _Float16 f16;
typedef f16 f16x8 __attribute__((ext_vector_type(8)));
typedef f16 f16x4 __attribute__((ext_vector_type(4)));
typedef float f32x4 __attribute__((ext_vector_type(4)));

#define DDIM    256
#define KCODES  1024
#define NTOK    65536
#define SMARGIN 0.1f   // score-space margin; == 0.2 in d2 units (d2 gap = 2*score gap)

// ---------------- prep: codebook fp32 -> A-fragment-tiled f16, c2, zero count ----
// Tiled layout: cht[((ct*8 + kt)*64 + L)*8 + j] = f16(cb[ct*16 + (L&15)][kt*32 + (L>>4)*8 + j])
//   (exactly the 16x16x32 MFMA A-operand per-lane layout; verified round 4)
__global__ __launch_bounds__(256) void vq_prep(const float* __restrict__ cb,
                                               f16* __restrict__ cht,
                                               float* __restrict__ c2,
                                               unsigned* __restrict__ count) {
    const int k    = blockIdx.x * 4 + (threadIdx.x >> 6);
    const int lane = threadIdx.x & 63;
    const float4 v = *(const float4*)(cb + (size_t)k * DDIM + 4 * lane);
    f16x4 h; h[0] = (f16)v.x; h[1] = (f16)v.y; h[2] = (f16)v.z; h[3] = (f16)v.w;
    const int ct = k >> 4, m = k & 15;
    const int e  = 4 * lane;            // this thread's 4 consecutive k-elements
    const int kt = e >> 5;
    const int s  = (e & 31) >> 3;       // sub-lane group within k-tile
    const int j0 = e & 7;               // 0 or 4
    const int L  = s * 16 + m;          // fragment lane
    *(f16x4*)(cht + ((size_t)(ct * 8 + kt) * 64 + L) * 8 + j0) = h;
    float ssum = v.x * v.x + v.y * v.y + v.z * v.z + v.w * v.w;
    #pragma unroll
    for (int off = 32; off > 0; off >>= 1) ssum += __shfl_down(ssum, off, 64);
    if (lane == 0) c2[k] = ssum;
    if (blockIdx.x == 0 && threadIdx.x == 0) *count = 0u;
}

// one k-slice: 16 MFMAs consuming CUR, then reload CUR with slice NS from NPTR
#define SLICE(CUR, S, NPTR, NS) do {                                                \
    _Pragma("unroll")                                                               \
    for (int ci = 0; ci < 4; ++ci)                                                  \
        _Pragma("unroll")                                                           \
        for (int ti = 0; ti < 4; ++ti)                                              \
            acc[ci][ti] = __builtin_amdgcn_mfma_f32_16x16x32_f16(                   \
                CUR[ci], bfrag[ti][S], acc[ci][ti], 0, 0, 0);                       \
    _Pragma("unroll")                                                               \
    for (int ci = 0; ci < 4; ++ci)                                                  \
        CUR[ci] = *(const f16x8*)((NPTR) + ci * 4096 + (NS) * 512);                 \
} while (0)

// ---------------- main: L2-streamed pipelined MFMA + register argmax + gather -----
__global__ __launch_bounds__(256, 2) void vq_main(const float* __restrict__ xg,
                                                  const f16* __restrict__ cht,
                                                  const float* __restrict__ c2,
                                                  const float* __restrict__ cb,
                                                  float* __restrict__ out,
                                                  unsigned* __restrict__ count,
                                                  unsigned* __restrict__ list) {
    __shared__ float c2s[KCODES];
    __shared__ float wmv[2][128];              // per code-half best score
    __shared__ int   wmi[2][128];
    __shared__ float wms[2][128];              // per code-half second score
    __shared__ int   idx_s[128];

    const int t    = threadIdx.x;
    const int wave = t >> 6, lane = t & 63;
    const int wm   = wave >> 1;                // code-half (M)
    const int tn   = wave & 1;                 // token-half (N)
    const int q    = lane >> 4;                // operand quad
    const int m16  = lane & 15;
    const int tok0 = blockIdx.x * 128;

    // ---- c2 staging + the only barrier, FIRST (nothing outstanding to drain) ----
    *(float4*)&c2s[t * 4] = *(const float4*)(c2 + t * 4);
    __syncthreads();

    const f16* aw = cht + wm * 16384 + lane * 8;   // wave's A-fragment base (r4 layout)

    // ---- issue chunk-0 slices 0,1 into the af double-buffer (covered by bfrag) ----
    f16x8 afA[4], afB[4];
    #pragma unroll
    for (int ci = 0; ci < 4; ++ci) afA[ci] = *(const f16x8*)(aw + ci * 4096 + 0 * 512);
    #pragma unroll
    for (int ci = 0; ci < 4; ++ci) afB[ci] = *(const f16x8*)(aw + ci * 4096 + 1 * 512);

    // ---- load token B-fragments, fp32 -> f16 in registers (once; verified) ----
    f16x8 bfrag[4][8];
    #pragma unroll
    for (int ti = 0; ti < 4; ++ti) {
        const size_t row = (size_t)(tok0 + tn * 64 + ti * 16 + m16) * DDIM;
        #pragma unroll
        for (int ks = 0; ks < 8; ++ks) {
            const float* p = xg + row + ks * 32 + q * 8;
            const float4 u0 = *(const float4*)(p);
            const float4 u1 = *(const float4*)(p + 4);
            f16x8 b;
            b[0] = (f16)u0.x; b[1] = (f16)u0.y; b[2] = (f16)u0.z; b[3] = (f16)u0.w;
            b[4] = (f16)u1.x; b[5] = (f16)u1.y; b[6] = (f16)u1.z; b[7] = (f16)u1.w;
            bfrag[ti][ks] = b;
        }
    }

    // running top-2 per ti over this wave's code-half, in registers
    float rb1[4], rb2[4]; int ri1[4];
    #pragma unroll
    for (int ti = 0; ti < 4; ++ti) { rb1[ti] = -FLT_MAX; rb2[ti] = -FLT_MAX; ri1[ti] = 0; }

    #pragma unroll 1
    for (int nc = 0; nc < 8; ++nc) {           // 8 chunks of 128 codes
        f32x4 acc[4][4];                       // [ci][ti], init = -0.5*c2 (score space)
        #pragma unroll
        for (int ci = 0; ci < 4; ++ci) {
            f32x4 cv = *(const f32x4*)&c2s[nc * 128 + wm * 64 + ci * 16 + q * 4];
            cv = cv * -0.5f;
            #pragma unroll
            for (int ti = 0; ti < 4; ++ti) acc[ci][ti] = cv;
        }

        const f16* an = aw + nc * 32768;
        const f16* ax = aw + ((nc + 1) & 7) * 32768;   // next chunk (wrap: harmless dead loads)

        __builtin_amdgcn_s_setprio(1);
        SLICE(afA, 0, an, 2);                  // consume slice s, reload buffer with s+2
        SLICE(afB, 1, an, 3);
        SLICE(afA, 2, an, 4);
        SLICE(afB, 3, an, 5);
        SLICE(afA, 4, an, 6);
        SLICE(afB, 5, an, 7);
        SLICE(afA, 6, ax, 0);                  // prefetch next chunk's slice 0
        SLICE(afB, 7, ax, 1);                  // ... and slice 1 (epilogue covers them)
        __builtin_amdgcn_s_setprio(0);

        // ---- chunk epilogue: per-token top-2 over this half's 64 codes (verified) ----
        const int kbase = nc * 128 + wm * 64;
        #pragma unroll
        for (int ti = 0; ti < 4; ++ti) {
            float b1 = -FLT_MAX, b2 = -FLT_MAX; int i1 = 0;
            #pragma unroll
            for (int ci = 0; ci < 4; ++ci) {   // ascending code order within lane
                #pragma unroll
                for (int r = 0; r < 4; ++r) {
                    const float v = acc[ci][ti][r];
                    const int   c = kbase + ci * 16 + q * 4 + r;
                    const bool gt = v > b1;    // strict: tie keeps lower index
                    b2 = fmaxf(b2, gt ? b1 : v);
                    i1 = gt ? c : i1;
                    b1 = gt ? v : b1;
                }
            }
            #pragma unroll
            for (int sft = 0; sft < 2; ++sft) {  // merge quads (l^16, l^32)
                const int off = 16 << sft;
                const float ob1 = __shfl_xor(b1, off, 64);
                const float ob2 = __shfl_xor(b2, off, 64);
                const int   oi1 = __shfl_xor(i1, off, 64);
                const bool better = (ob1 > b1) || (ob1 == b1 && oi1 < i1);
                b2 = fmaxf(fmaxf(b2, ob2), fminf(b1, ob1));
                b1 = better ? ob1 : b1;
                i1 = better ? oi1 : i1;
            }
            // fold into running (ascending nc -> earlier chunk wins ties)
            rb2[ti] = fmaxf(fmaxf(rb2[ti], b2), fminf(rb1[ti], b1));
            if (b1 > rb1[ti]) { rb1[ti] = b1; ri1[ti] = i1; }
        }
    }

    // ---- publish per-half results, merge halves, flag, gather (verified r4) ----
    #pragma unroll
    for (int ti = 0; ti < 4; ++ti) {
        if (lane < 16) {
            const int tl = tn * 64 + ti * 16 + m16;
            wmv[wm][tl] = rb1[ti]; wmi[wm][tl] = ri1[ti]; wms[wm][tl] = rb2[ti];
        }
    }
    __syncthreads();
    if (t < 128) {
        const float a1 = wmv[0][t], a2 = wms[0][t];
        const int   ai = wmi[0][t];
        const float b1_ = wmv[1][t], b2_ = wms[1][t];
        const int   bi_ = wmi[1][t];
        const bool bb = (b1_ > a1) || (b1_ == a1 && bi_ < ai);
        const float c1 = bb ? b1_ : a1;
        const int   ci_ = bb ? bi_ : ai;
        const float cs = fmaxf(fmaxf(a2, b2_), fminf(a1, b1_));
        idx_s[t] = ci_;
        if (c1 - cs < SMARGIN) {               // d2 gap = 2*(c1-cs) < 0.2
            const unsigned p = atomicAdd(count, 1u);
            list[p] = tok0 + t;
        }
    }
    __syncthreads();

    // gather epilogue: out[tok] = cb[argmin], coalesced float4
    #pragma unroll
    for (int i = 0; i < 32; ++i) {
        const int f   = i * 256 + t;           // 8192 float4 = 128 tok x 64
        const int tok = f >> 6, d4 = f & 63;
        const int code = idx_s[tok];
        const float4 v = *(const float4*)(cb + (size_t)code * DDIM + 4 * d4);
        *(float4*)(out + (size_t)(tok0 + tok) * DDIM + 4 * d4) = v;
    }
}

// ---------------- rescue: exact fp32 argmin for margin-flagged tokens ----------------
// (verified round 5: 8 tokens/iter, no spill, grid-stride 1024)
__global__ __launch_bounds__(256) void vq_rescue(const float* __restrict__ xg,
                                                 const float* __restrict__ cb,
                                                 const float* __restrict__ c2,
                                                 const unsigned* __restrict__ count,
                                                 const unsigned* __restrict__ list,
                                                 float* __restrict__ out) {
    __shared__ float xls[8][DDIM];             // 8 KB
    __shared__ float rv[4][8];
    __shared__ int   ri[4][8];
    __shared__ int   bidx[8];

    const int t = threadIdx.x;
    const int wave = t >> 6, lane = t & 63;
    const unsigned n = *count;

    for (unsigned base = blockIdx.x * 8; base < n; base += gridDim.x * 8) {
        const int nb = (int)min(8u, n - base);
        __syncthreads();                        // protect xls/rv/bidx reuse
        #pragma unroll
        for (int i = 0; i < 2; ++i) {
            const int f = t + 256 * i;          // 512 float4 slots
            const int row = f >> 6, d4 = f & 63;
            if (row < nb)
                *(float4*)&xls[row][4 * d4] =
                    *(const float4*)(xg + (size_t)list[base + row] * DDIM + 4 * d4);
        }
        __syncthreads();

        float acc[4][8];
        #pragma unroll
        for (int j = 0; j < 4; ++j)
            #pragma unroll
            for (int tk = 0; tk < 8; ++tk) acc[j][tk] = 0.0f;

        for (int d4 = 0; d4 < 64; ++d4) {
            float4 cv[4];
            #pragma unroll
            for (int j = 0; j < 4; ++j)
                cv[j] = *(const float4*)(cb + (size_t)(4 * t + j) * DDIM + 4 * d4);
            #pragma unroll
            for (int tk = 0; tk < 8; ++tk) {
                const float4 xv = *(const float4*)&xls[tk][4 * d4];
                #pragma unroll
                for (int j = 0; j < 4; ++j) {
                    float a = acc[j][tk];       // sequential .x->.w: verified order
                    a = fmaf(cv[j].x, xv.x, a);
                    a = fmaf(cv[j].y, xv.y, a);
                    a = fmaf(cv[j].z, xv.z, a);
                    a = fmaf(cv[j].w, xv.w, a);
                    acc[j][tk] = a;
                }
            }
        }

        // per-token argmin: thread's 4 codes -> wave butterfly -> cross-wave merge
        #pragma unroll
        for (int tk = 0; tk < 8; ++tk) {
            if (tk < nb) {
                float b1 = FLT_MAX; int i1 = 0;
                #pragma unroll
                for (int j = 0; j < 4; ++j) {   // codes 4t..4t+3 ascending
                    const float d = fmaf(-2.0f, acc[j][tk], c2[4 * t + j]);
                    if (d < b1) { b1 = d; i1 = 4 * t + j; }
                }
                #pragma unroll
                for (int off = 32; off > 0; off >>= 1) {
                    const float ov = __shfl_xor(b1, off, 64);
                    const int   oi = __shfl_xor(i1, off, 64);
                    if (ov < b1 || (ov == b1 && oi < i1)) { b1 = ov; i1 = oi; }
                }
                if (lane == 0) { rv[wave][tk] = b1; ri[wave][tk] = i1; }
            }
        }
        __syncthreads();
        if (t < 8 && t < nb) {                  // ascending wave order: same tiebreak
            float bv = rv[0][t]; int bi = ri[0][t];
            #pragma unroll
            for (int w = 1; w < 4; ++w)
                if (rv[w][t] < bv || (rv[w][t] == bv && ri[w][t] < bi)) {
                    bv = rv[w][t]; bi = ri[w][t];
                }
            bidx[t] = bi;
        }
        __syncthreads();

        #pragma unroll
        for (int i = 0; i < 2; ++i) {
            const int f = t + 256 * i;
            const int row = f >> 6, d4 = f & 63;
            if (row < nb) {
                const int code = bidx[row];
                const float4 v = *(const float4*)(cb + (size_t)code * DDIM + 4 * d4);
                *(float4*)(out + (size_t)list[base + row] * DDIM + 4 * d4) = v;
            }
        }
    }
}

extern "C" void kernel_launch(void* const* d_in, const int* in_sizes, int n_in,
                              void* d_out, int out_size, void* d_ws, size_t ws_size,
                              hipStream_t stream) {
    const float* x  = (const float*)d_in[0];   // [B,T,D] fp32
    const float* cb = (const float*)d_in[1];   // [K,D]   fp32
    float* out = (float*)d_out;

    char* ws = (char*)d_ws;
    f16*      cht   = (f16*)ws;                              // 524288 B (tiled)
    float*    c2    = (float*)(ws + 524288);                 // 4096 B
    unsigned* count = (unsigned*)(ws + 528448);              // 4 B (padded)
    unsigned* list  = (unsigned*)(ws + 528512);              // 262144 B

    hipLaunchKernelGGL(vq_prep,   dim3(KCODES / 4), dim3(256), 0, stream, cb, cht, c2, count);
    hipLaunchKernelGGL(vq_main,   dim3(NTOK / 128), dim3(256), 0, stream,
                       x, cht, c2, cb, out, count, list);
    hipLaunchKernelGGL(vq_rescue, dim3(1024),       dim3(256), 0, stream,
                       x, cb, c2, count, list, out);
}